// Round 11
// baseline (260.341 us; speedup 1.0000x reference)
//
#include <hip/hip_runtime.h>
#include <stdint.h>

#define N 8192
#define NCLS 80
#define CCAP 128            // per-class member cap (expected ~51; >10 sigma)

// Within-class order key: ascending key == descending conf (conf>0.5 =>
// positive => bit-monotonic), tie -> lower index. Identical relative order
// to the reference's global stable argsort restricted to one class.
__device__ __forceinline__ unsigned long long makeKey(float c, int idx) {
    return ((unsigned long long)(~__float_as_uint(c)) << 32) | (unsigned int)idx;
}

// ---------------- single kernel: argmax + per-class exact NMS -----------
// 512 blocks x 256 thr, ZERO inter-block synchronization (no grid.sync,
// no handshake -- both measured slower, rounds 2 & 10).
//  * owner part (all blocks): 16-thread cooperative argmax for its 16
//    elements -> cls channel; full zero rows for invalid elements.
//  * class part (blocks 0..79): recompute membership argmax, but
//    COALESCED (round-8 lesson: transactions, not bytes): compact valid
//    indices from a float4 conf scan into LDS, then 16-thread-cooperative
//    argmax per valid element (wave reads 4 contiguous 256B+64B segments
//    vs round 8's 64 scattered lines/instr). Argmax is pure comparison
//    logic => recomputation is bit-identical to the owner path.
//    Cross-class pairs never suppress and the global stable sort
//    preserves within-class relative order, so the reference's global
//    greedy scan decomposes exactly into 80 per-class scans (validated
//    bit-exact rounds 6-10, absmax 0.0 every round).
__global__ __launch_bounds__(256) void k_all(
    const float* __restrict__ box,
    const float* __restrict__ conf,
    const float* __restrict__ logits,
    float* __restrict__ out)
{
#pragma clang fp contract(off)
    const int tid = threadIdx.x;
    const int bid = blockIdx.x;

    // ================= owner part: 16 elements, 16 threads each =========
    {
        const int i = bid * 16 + (tid >> 4);
        const int s = tid & 15;
        // thread s covers logits[4s..4s+3] (and [64+4s..67+4s] for s<4) in
        // ascending index order with strict > => first-max-wins; combine
        // prefers greater value, tie -> lower index => exact argmax.
        const float4* lp4 = (const float4*)(logits + (size_t)i * NCLS);
        float4 v = lp4[s];
        int bi = 4 * s;
        float best = v.x;
        if (v.y > best) { best = v.y; bi = 4 * s + 1; }
        if (v.z > best) { best = v.z; bi = 4 * s + 2; }
        if (v.w > best) { best = v.w; bi = 4 * s + 3; }
        if (s < 4) {
            float4 w = lp4[16 + s];
            int b1 = 64 + 4 * s;
            if (w.x > best) { best = w.x; bi = b1; }
            if (w.y > best) { best = w.y; bi = b1 + 1; }
            if (w.z > best) { best = w.z; bi = b1 + 2; }
            if (w.w > best) { best = w.w; bi = b1 + 3; }
        }
        for (int off = 8; off; off >>= 1) {
            float ob = __shfl_down(best, off, 16);
            int   oi = __shfl_down(bi, off, 16);
            if (ob > best || (ob == best && oi < bi)) { best = ob; bi = oi; }
        }
        if (s == 0) {
            out[5 * N + i] = (float)bi;
            if (!(conf[i] > 0.5f)) {         // invalid: full zero row here
                out[i * 5 + 0] = 0.0f;
                out[i * 5 + 1] = 0.0f;
                out[i * 5 + 2] = 0.0f;
                out[i * 5 + 3] = 0.0f;
                out[i * 5 + 4] = 0.0f;
                out[6 * N + i] = 0.0f;
            }
        }
    }

    if (bid >= NCLS) return;

    // ================= class part: exact NMS for class c = bid ==========
    __shared__ unsigned short vlist[N / 2 * 2];     // 8192 u16 = 16 KB
    __shared__ int nv, n;
    __shared__ unsigned short uidx[CCAP];           // unsorted member idx
    __shared__ unsigned long long ukey[CCAP];
    __shared__ unsigned short sidx[CCAP];           // sorted by class rank
    __shared__ float4 sbox[CCAP];                   // corners x1,y1,x2,y2
    __shared__ float  sar[CCAP];
    __shared__ unsigned long long supmat[CCAP][2];  // bit b: a suppresses b
    __shared__ unsigned long long keepm[2];

    const int cls = bid;
    if (tid == 0) { nv = 0; n = 0; }
    supmat[tid >> 1][tid & 1] = 0ULL;               // 256 words, 1/thread
    __syncthreads();

    // phase 0: compact valid indices (coalesced float4 conf scan)
    for (int q = tid; q < N / 4; q += 256) {
        float4 c4 = ((const float4*)conf)[q];
        int base = q * 4;
        if (c4.x > 0.5f) vlist[atomicAdd(&nv, 1)] = (unsigned short)(base + 0);
        if (c4.y > 0.5f) vlist[atomicAdd(&nv, 1)] = (unsigned short)(base + 1);
        if (c4.z > 0.5f) vlist[atomicAdd(&nv, 1)] = (unsigned short)(base + 2);
        if (c4.w > 0.5f) vlist[atomicAdd(&nv, 1)] = (unsigned short)(base + 3);
    }
    __syncthreads();
    const int NV = nv;

    // phase 1: cooperative membership argmax over the valid list
    {
        const int g = tid >> 4;                     // group 0..15
        const int s = tid & 15;
        for (int vi = g; vi < NV; vi += 16) {
            const int i = vlist[vi];
            const float4* lp4 = (const float4*)(logits + (size_t)i * NCLS);
            float4 v = lp4[s];
            int bi = 4 * s;
            float best = v.x;
            if (v.y > best) { best = v.y; bi = 4 * s + 1; }
            if (v.z > best) { best = v.z; bi = 4 * s + 2; }
            if (v.w > best) { best = v.w; bi = 4 * s + 3; }
            if (s < 4) {
                float4 w = lp4[16 + s];
                int b1 = 64 + 4 * s;
                if (w.x > best) { best = w.x; bi = b1; }
                if (w.y > best) { best = w.y; bi = b1 + 1; }
                if (w.z > best) { best = w.z; bi = b1 + 2; }
                if (w.w > best) { best = w.w; bi = b1 + 3; }
            }
            for (int off = 8; off; off >>= 1) {
                float ob = __shfl_down(best, off, 16);
                int   oi = __shfl_down(bi, off, 16);
                if (ob > best || (ob == best && oi < bi)) { best = ob; bi = oi; }
            }
            if (s == 0 && bi == cls) {
                int p = atomicAdd(&n, 1);
                if (p < CCAP) {
                    uidx[p] = (unsigned short)i;
                    ukey[p] = makeKey(conf[i], i);
                }
            }
        }
    }
    __syncthreads();
    int nn = n; if (nn > CCAP) nn = CCAP;

    // exact in-class rank (stable key) + scatter + stage geometry
    if (tid < nn) {
        unsigned long long mk = ukey[tid];
        int r = 0;
        for (int k = 0; k < nn; ++k) r += (ukey[k] < mk) ? 1 : 0;
        int i = uidx[tid];
        float4 b = ((const float4*)box)[i];          // x, y, w, h
        float hw = b.z * 0.5f, hh = b.w * 0.5f;      // == w/2 exactly
        sidx[r] = (unsigned short)i;
        sbox[r] = make_float4(b.x - hw, b.y - hh, b.x + hw, b.y + hh);
        sar[r]  = b.z * b.w;
    }
    __syncthreads();

    // pairwise IoU -> suppression bits (a = earlier rank, b = later)
    const int total = nn * nn;
    for (int t = tid; t < total; t += 256) {
        int a = t / nn, b = t - a * nn;
        if (b > a) {
            float4 A = sbox[a], B = sbox[b];
            // exact float32 op order of the reference:
            float iw = fminf(A.z, B.z) - fmaxf(A.x, B.x);
            iw = fmaxf(iw, 0.0f);
            float ih = fminf(A.w, B.w) - fmaxf(A.y, B.y);
            ih = fmaxf(ih, 0.0f);
            float inter = iw * ih;
            float uni = sar[a] + sar[b] - inter;
            float iou = __fdiv_rn(inter, uni);       // IEEE-rounded divide
            if (iou > 0.5f)
                atomicOr(&supmat[a][b >> 6], 1ULL << (b & 63));
        }
    }
    __syncthreads();

    // sequential greedy scan (reference semantics, bit-exact): a kept row
    // clears its marked later rows; supmat[a] holds only bits b>a.
    if (tid == 0) {
        unsigned long long k0 = (nn >= 64) ? ~0ULL : ((1ULL << nn) - 1ULL);
        unsigned long long k1 = (nn >= 128) ? ~0ULL
                              : (nn > 64) ? ((1ULL << (nn - 64)) - 1ULL) : 0ULL;
        for (int a = 0; a < nn; ++a) {
            bool ka = (a < 64) ? ((k0 >> a) & 1ULL) : ((k1 >> (a - 64)) & 1ULL);
            if (ka) { k0 &= ~supmat[a][0]; k1 &= ~supmat[a][1]; }
        }
        keepm[0] = k0; keepm[1] = k1;
    }
    __syncthreads();

    // output rows for this class's members (box/conf re-reads are L2-hot)
    if (tid < nn) {
        int i = sidx[tid];
        float m = (float)((keepm[tid >> 6] >> (tid & 63)) & 1ULL);
        float4 b = ((const float4*)box)[i];
        out[i * 5 + 0] = b.x * m;
        out[i * 5 + 1] = b.y * m;
        out[i * 5 + 2] = b.z * m;
        out[i * 5 + 3] = b.w * m;
        out[i * 5 + 4] = conf[i] * m;
        out[6 * N + i] = m;
    }
}

// ---------------- launch -------------------------------------------------
extern "C" void kernel_launch(void* const* d_in, const int* in_sizes, int n_in,
                              void* d_out, int out_size, void* d_ws, size_t ws_size,
                              hipStream_t stream) {
    const float* box    = (const float*)d_in[0];
    const float* conf   = (const float*)d_in[1];
    const float* logits = (const float*)d_in[2];
    float* out = (float*)d_out;

    k_all<<<N / 16, 256, 0, stream>>>(box, conf, logits, out);
}

// Round 12
// 71.875 us; speedup vs baseline: 3.6221x; 3.6221x over previous
//
#include <hip/hip_runtime.h>
#include <stdint.h>

#define N 8192
#define NCLS 80
#define CCAP 128            // per-class member cap (expected ~51; >10 sigma)

// Within-class order key: ascending key == descending conf (conf>0.5 =>
// positive => bit-monotonic), tie -> lower index. Identical relative order
// to the reference's global stable argsort restricted to one class.
__device__ __forceinline__ unsigned long long makeKey(float c, int idx) {
    return ((unsigned long long)(~__float_as_uint(c)) << 32) | (unsigned int)idx;
}

// ---------------- K1: argmax + cls channel + invalid rows ---------------
// 512 blocks x 256 thr; 16 threads per element, float4-cooperative logits
// read (coalesced; validated rounds 6-9). Writes cls for ALL rows (u8
// array for K2 + float channel), full zero rows for invalid elements.
// NOTE (rounds 8/10/11): fusing K2 into this dispatch was measured slower
// via ALL three mechanisms (grid.sync 151us, spin-handshake 161us,
// redundant recompute 136/260us) -- the ~5us boundary is the cheapest
// way to communicate the all-to-all cls dependency. Keep two dispatches.
__global__ __launch_bounds__(256) void k_cls(
    const float* __restrict__ conf,
    const float* __restrict__ logits,
    unsigned char* __restrict__ cls8,
    float* __restrict__ out)
{
    const int tid = threadIdx.x;
    const int i = blockIdx.x * 16 + (tid >> 4);
    const int s = tid & 15;

    // thread s covers logits[4s..4s+3] (and [64+4s..67+4s] for s<4) in
    // ascending index order with strict > => first-max-wins; combine
    // prefers greater value, tie -> lower index => exact argmax.
    const float4* lp4 = (const float4*)(logits + (size_t)i * NCLS);
    float4 v = lp4[s];
    int bi = 4 * s;
    float best = v.x;
    if (v.y > best) { best = v.y; bi = 4 * s + 1; }
    if (v.z > best) { best = v.z; bi = 4 * s + 2; }
    if (v.w > best) { best = v.w; bi = 4 * s + 3; }
    if (s < 4) {
        float4 w = lp4[16 + s];
        int b1 = 64 + 4 * s;
        if (w.x > best) { best = w.x; bi = b1; }
        if (w.y > best) { best = w.y; bi = b1 + 1; }
        if (w.z > best) { best = w.z; bi = b1 + 2; }
        if (w.w > best) { best = w.w; bi = b1 + 3; }
    }
    for (int off = 8; off; off >>= 1) {
        float ob = __shfl_down(best, off, 16);
        int   oi = __shfl_down(bi, off, 16);
        if (ob > best || (ob == best && oi < bi)) { best = ob; bi = oi; }
    }

    if (s == 0) {
        cls8[i] = (unsigned char)bi;
        out[5 * N + i] = (float)bi;
        if (!(conf[i] > 0.5f)) {         // invalid: full zero row here
            out[i * 5 + 0] = 0.0f;
            out[i * 5 + 1] = 0.0f;
            out[i * 5 + 2] = 0.0f;
            out[i * 5 + 3] = 0.0f;
            out[i * 5 + 4] = 0.0f;
            out[6 * N + i] = 0.0f;
        }
    }
}

// ---------------- K2: per-class exact NMS + valid-row outputs -----------
// One block per class, 512 threads (8 waves/CU for latency hiding in the
// bucket scan -- round 11 lesson: wave count, not transaction count, was
// the limiter at low occupancy). Cross-class pairs never suppress
// (same_cls gate), and the global stable sort preserves within-class
// relative order, so the reference's global greedy scan decomposes
// exactly into 80 independent per-class greedy scans (validated
// bit-exact, rounds 6-11, absmax 0.0 every round). Bucket scan is
// vectorized: float4 conf + one uint of 4 packed u8 cls per iteration.
__global__ __launch_bounds__(512) void k_nms(
    const float* __restrict__ box,
    const float* __restrict__ conf,
    const unsigned char* __restrict__ cls8,
    float* __restrict__ out)
{
#pragma clang fp contract(off)
    __shared__ int n;
    __shared__ unsigned short uidx[CCAP];           // unsorted member idx
    __shared__ unsigned long long ukey[CCAP];
    __shared__ unsigned short sidx[CCAP];           // sorted by class rank
    __shared__ float4 sbox[CCAP];                   // corners x1,y1,x2,y2
    __shared__ float  sar[CCAP];
    __shared__ unsigned long long supmat[CCAP][2];  // bit b: a suppresses b
    __shared__ unsigned long long keepm[2];

    const int tid = threadIdx.x;
    const int cls = blockIdx.x;

    if (tid == 0) n = 0;
    if (tid < 256) supmat[tid >> 1][tid & 1] = 0ULL;   // 256 words
    __syncthreads();

    // bucket this class's valid members (4 elements per iteration)
    for (int q = tid; q < N / 4; q += 512) {
        float4 c4 = ((const float4*)conf)[q];
        unsigned int k4 = ((const unsigned int*)cls8)[q];
        int base = q * 4;
        if (c4.x > 0.5f && (k4 & 0xffu) == (unsigned)cls) {
            int p = atomicAdd(&n, 1);
            if (p < CCAP) { uidx[p] = (unsigned short)(base + 0); ukey[p] = makeKey(c4.x, base + 0); }
        }
        if (c4.y > 0.5f && ((k4 >> 8) & 0xffu) == (unsigned)cls) {
            int p = atomicAdd(&n, 1);
            if (p < CCAP) { uidx[p] = (unsigned short)(base + 1); ukey[p] = makeKey(c4.y, base + 1); }
        }
        if (c4.z > 0.5f && ((k4 >> 16) & 0xffu) == (unsigned)cls) {
            int p = atomicAdd(&n, 1);
            if (p < CCAP) { uidx[p] = (unsigned short)(base + 2); ukey[p] = makeKey(c4.z, base + 2); }
        }
        if (c4.w > 0.5f && ((k4 >> 24) & 0xffu) == (unsigned)cls) {
            int p = atomicAdd(&n, 1);
            if (p < CCAP) { uidx[p] = (unsigned short)(base + 3); ukey[p] = makeKey(c4.w, base + 3); }
        }
    }
    __syncthreads();
    int nn = n; if (nn > CCAP) nn = CCAP;

    // exact in-class rank (stable key) + scatter + stage geometry
    if (tid < nn) {
        unsigned long long mk = ukey[tid];
        int r = 0;
        for (int k = 0; k < nn; ++k) r += (ukey[k] < mk) ? 1 : 0;
        int i = uidx[tid];
        float4 b = ((const float4*)box)[i];          // x, y, w, h
        float hw = b.z * 0.5f, hh = b.w * 0.5f;      // == w/2 exactly
        sidx[r] = (unsigned short)i;
        sbox[r] = make_float4(b.x - hw, b.y - hh, b.x + hw, b.y + hh);
        sar[r]  = b.z * b.w;
    }
    __syncthreads();

    // pairwise IoU -> suppression bits (a = earlier rank, b = later)
    const int total = nn * nn;
    for (int t = tid; t < total; t += 512) {
        int a = t / nn, b = t - a * nn;
        if (b > a) {
            float4 A = sbox[a], B = sbox[b];
            // exact float32 op order of the reference:
            float iw = fminf(A.z, B.z) - fmaxf(A.x, B.x);
            iw = fmaxf(iw, 0.0f);
            float ih = fminf(A.w, B.w) - fmaxf(A.y, B.y);
            ih = fmaxf(ih, 0.0f);
            float inter = iw * ih;
            float uni = sar[a] + sar[b] - inter;
            float iou = __fdiv_rn(inter, uni);       // IEEE-rounded divide
            if (iou > 0.5f)
                atomicOr(&supmat[a][b >> 6], 1ULL << (b & 63));
        }
    }
    __syncthreads();

    // sequential greedy scan (reference semantics, bit-exact): a kept row
    // clears its marked later rows; supmat[a] holds only bits b>a.
    if (tid == 0) {
        unsigned long long k0 = (nn >= 64) ? ~0ULL : ((1ULL << nn) - 1ULL);
        unsigned long long k1 = (nn >= 128) ? ~0ULL
                              : (nn > 64) ? ((1ULL << (nn - 64)) - 1ULL) : 0ULL;
        for (int a = 0; a < nn; ++a) {
            bool ka = (a < 64) ? ((k0 >> a) & 1ULL) : ((k1 >> (a - 64)) & 1ULL);
            if (ka) { k0 &= ~supmat[a][0]; k1 &= ~supmat[a][1]; }
        }
        keepm[0] = k0; keepm[1] = k1;
    }
    __syncthreads();

    // output rows for this class's members (box/conf re-reads are L2-hot)
    if (tid < nn) {
        int i = sidx[tid];
        float m = (float)((keepm[tid >> 6] >> (tid & 63)) & 1ULL);
        float4 b = ((const float4*)box)[i];
        out[i * 5 + 0] = b.x * m;
        out[i * 5 + 1] = b.y * m;
        out[i * 5 + 2] = b.z * m;
        out[i * 5 + 3] = b.w * m;
        out[i * 5 + 4] = conf[i] * m;
        out[6 * N + i] = m;
    }
}

// ---------------- launch -------------------------------------------------
extern "C" void kernel_launch(void* const* d_in, const int* in_sizes, int n_in,
                              void* d_out, int out_size, void* d_ws, size_t ws_size,
                              hipStream_t stream) {
    const float* box    = (const float*)d_in[0];
    const float* conf   = (const float*)d_in[1];
    const float* logits = (const float*)d_in[2];
    float* out = (float*)d_out;

    unsigned char* cls8 = (unsigned char*)d_ws;      // 8 KB

    k_cls<<<N / 16, 256, 0, stream>>>(conf, logits, cls8, out);
    k_nms<<<NCLS, 512, 0, stream>>>(box, conf, cls8, out);
}